// Round 1
// baseline (339.139 us; speedup 1.0000x reference)
//
#include <hip/hip_runtime.h>

typedef __attribute__((ext_vector_type(8))) short bf16x8;
typedef __attribute__((ext_vector_type(4))) float f32x4;
typedef __attribute__((ext_vector_type(4))) unsigned int uint4v;
typedef unsigned short ushort_t;

// Problem constants
#define BB 2
#define TT 2048
#define CC 1024
#define HH 16
#define HD 64
#define MM (BB * TT)       // 4096
#define N3C (3 * CC)       // 3072

__device__ __forceinline__ ushort_t f2b(float f) {
  unsigned u = __builtin_bit_cast(unsigned, f);
  u += 0x7fffu + ((u >> 16) & 1u);   // RNE
  return (ushort_t)(u >> 16);
}

__device__ __forceinline__ f32x4 mfma16(bf16x8 a, bf16x8 b, f32x4 c) {
  return __builtin_amdgcn_mfma_f32_16x16x32_bf16(a, b, c, 0, 0, 0);
}

// ---------------- cast x (f32 -> bf16), 4 elems/thread ----------------
__global__ __launch_bounds__(256) void cast_f32_bf16(const float* __restrict__ x,
                                                     ushort_t* __restrict__ o, int n4) {
  int i = blockIdx.x * 256 + threadIdx.x;
  if (i >= n4) return;
  const float4 v = ((const float4*)x)[i];
  typedef __attribute__((ext_vector_type(4))) ushort_t us4;
  us4 r;
  r.x = f2b(v.x); r.y = f2b(v.y); r.z = f2b(v.z); r.w = f2b(v.w);
  ((us4*)o)[i] = r;
}

// ------------- transpose + cast: W[R,Nc] f32 -> Wt[Nc,R] bf16 -------------
__global__ __launch_bounds__(256) void transpose_cast(const float* __restrict__ W,
                                                      ushort_t* __restrict__ Wt,
                                                      int R, int Nc) {
  __shared__ ushort_t tile[32][33];
  int n0 = blockIdx.x * 32, r0 = blockIdx.y * 32;
  int c = threadIdx.x, rr = threadIdx.y;  // 32 x 8
#pragma unroll
  for (int i = 0; i < 4; ++i) {
    int r = rr + i * 8;
    tile[r][c] = f2b(W[(size_t)(r0 + r) * Nc + n0 + c]);
  }
  __syncthreads();
#pragma unroll
  for (int i = 0; i < 4; ++i) {
    int r = rr + i * 8;  // n-index within block
    Wt[(size_t)(n0 + r) * R + r0 + c] = tile[c][r];
  }
}

// ---------------- MFMA GEMM: C[M,N] = A[M,K] * Bt[N,K]^T + bias ----------------
// EPI 0: scatter bf16 into q[B,H,T,64], k[B,H,T,64], vT[B,H,64,T]
// EPI 1: write f32 out[M,N]
template <int EPI>
__global__ __launch_bounds__(256) void gemm_bt(const ushort_t* __restrict__ A,
                                               const ushort_t* __restrict__ Bt,
                                               const float* __restrict__ bias,
                                               ushort_t* __restrict__ qo,
                                               ushort_t* __restrict__ ko,
                                               ushort_t* __restrict__ vto,
                                               float* __restrict__ outp,
                                               int N, int K) {
  __shared__ __align__(16) ushort_t As[128 * 32];
  __shared__ __align__(16) ushort_t Bs[128 * 32];
  const int tid = threadIdx.x, lane = tid & 63, wave = tid >> 6;
  const int l15 = lane & 15, quad = lane >> 4;
  const int wm = (wave >> 1) * 64, wn = (wave & 1) * 64;
  const int m0 = blockIdx.y * 128, n0 = blockIdx.x * 128;

  f32x4 acc[4][4] = {};
  for (int k0 = 0; k0 < K; k0 += 32) {
    __syncthreads();
#pragma unroll
    for (int p = 0; p < 2; ++p) {
      int e = (p * 256 + tid) * 8;
      int r = e >> 5, c = e & 31;
      *(uint4v*)&As[e] = *(const uint4v*)&A[(size_t)(m0 + r) * K + k0 + c];
      *(uint4v*)&Bs[e] = *(const uint4v*)&Bt[(size_t)(n0 + r) * K + k0 + c];
    }
    __syncthreads();
    bf16x8 af[4], bfr[4];
#pragma unroll
    for (int i = 0; i < 4; ++i) {
      af[i]  = *(const bf16x8*)&As[(wm + i * 16 + l15) * 32 + quad * 8];
      bfr[i] = *(const bf16x8*)&Bs[(wn + i * 16 + l15) * 32 + quad * 8];
    }
#pragma unroll
    for (int i = 0; i < 4; ++i)
#pragma unroll
      for (int j = 0; j < 4; ++j)
        acc[i][j] = mfma16(af[i], bfr[j], acc[i][j]);
  }

#pragma unroll
  for (int i = 0; i < 4; ++i) {
#pragma unroll
    for (int j = 0; j < 4; ++j) {
#pragma unroll
      for (int r = 0; r < 4; ++r) {
        int gr = m0 + wm + i * 16 + quad * 4 + r;   // row: C/D row = quad*4+reg
        int gc = n0 + wn + j * 16 + l15;            // col: C/D col = lane&15
        float v = acc[i][j][r] + bias[gc];
        if (EPI == 0) {
          int sec = gc >> 10, cc = gc & 1023, h = cc >> 6, d = cc & 63;
          int b = gr >> 11, t = gr & 2047;
          ushort_t hv = f2b(v);
          size_t hb = (size_t)(b * HH + h);
          if (sec == 0)      qo[(hb * TT + t) * HD + d] = hv;
          else if (sec == 1) ko[(hb * TT + t) * HD + d] = hv;
          else               vto[(hb * HD + d) * TT + t] = hv;
        } else {
          outp[(size_t)gr * N + gc] = v;
        }
      }
    }
  }
}

// ---------------- flash attention (causal), bf16 in, bf16 y out ----------------
// grid: (T/64, B*H); block 256 = 4 waves; wave w handles queries qb*64+w*16 .. +15
__global__ __launch_bounds__(256) void attn_kernel(const ushort_t* __restrict__ q,
                                                   const ushort_t* __restrict__ k,
                                                   const ushort_t* __restrict__ vt,
                                                   ushort_t* __restrict__ y) {
  __shared__ __align__(16) ushort_t Ks[32 * 64];      // [kk][d]
  __shared__ __align__(16) ushort_t Vs[64 * 32];      // [d][kk]  (V^T tile)
  __shared__ __align__(16) ushort_t Ps[4][16 * 32];   // per-wave P [row][kk]

  const int tid = threadIdx.x, lane = tid & 63, wave = tid >> 6;
  const int l15 = lane & 15, quad = lane >> 4;
  const int qb = blockIdx.x, bh = blockIdx.y;
  const int qs = qb * 64 + wave * 16;
  const size_t bho = (size_t)bh * (TT * HD);

  // Q A-fragments: A[m=l15][kdim=quad*8+j], two 32-wide d-halves
  bf16x8 aq0 = *(const bf16x8*)&q[bho + (size_t)(qs + l15) * HD + quad * 8];
  bf16x8 aq1 = *(const bf16x8*)&q[bho + (size_t)(qs + l15) * HD + 32 + quad * 8];

  f32x4 o[4] = {};
  float m_r[4] = {-__builtin_inff(), -__builtin_inff(), -__builtin_inff(), -__builtin_inff()};
  float l_r[4] = {};

  const int nk = qb * 2 + 2;  // 32-key tiles needed to cover diag of this 64-q block
  for (int it = 0; it < nk; ++it) {
    const int kb = it * 32;
    __syncthreads();
    {
      int e = tid * 8;
      // K tile: layout matches global row-major [t][d] directly
      *(uint4v*)&Ks[e] = *(const uint4v*)&k[bho + (size_t)kb * HD + e];
      // V^T tile
      int d = e >> 5, c = e & 31;
      *(uint4v*)&Vs[e] = *(const uint4v*)&vt[bho + (size_t)d * TT + kb + c];
    }
    __syncthreads();

    // S = Q K^T (two 16-key groups, K-dim = 64 over two mfmas)
    f32x4 s[2];
#pragma unroll
    for (int ng = 0; ng < 2; ++ng) {
      bf16x8 kf0 = *(const bf16x8*)&Ks[(ng * 16 + l15) * 64 + quad * 8];
      bf16x8 kf1 = *(const bf16x8*)&Ks[(ng * 16 + l15) * 64 + 32 + quad * 8];
      f32x4 z = {};
      z = mfma16(aq0, kf0, z);
      z = mfma16(aq1, kf1, z);
      s[ng] = z;
    }

    // scale + causal mask + row max
    float tmax[4] = {-__builtin_inff(), -__builtin_inff(), -__builtin_inff(), -__builtin_inff()};
#pragma unroll
    for (int ng = 0; ng < 2; ++ng) {
      int kg = kb + ng * 16 + l15;
#pragma unroll
      for (int r = 0; r < 4; ++r) {
        int qg = qs + quad * 4 + r;
        float v = s[ng][r] * 0.125f;
        v = (kg > qg) ? -__builtin_inff() : v;
        s[ng][r] = v;
        tmax[r] = fmaxf(tmax[r], v);
      }
    }
#pragma unroll
    for (int r = 0; r < 4; ++r) {
#pragma unroll
      for (int off = 1; off < 16; off <<= 1)
        tmax[r] = fmaxf(tmax[r], __shfl_xor(tmax[r], off));
      float mn = fmaxf(m_r[r], tmax[r]);
      float a = __expf(m_r[r] - mn);  // m_r=-inf on first tile -> a=0 (o is 0 anyway)
      m_r[r] = mn;
      l_r[r] *= a;
#pragma unroll
      for (int dg = 0; dg < 4; ++dg) o[dg][r] *= a;
    }

    // P = exp(s - m), row sums, stash P into LDS in A-operand-friendly layout
    float rs[4] = {};
#pragma unroll
    for (int ng = 0; ng < 2; ++ng) {
#pragma unroll
      for (int r = 0; r < 4; ++r) {
        float p = __expf(s[ng][r] - m_r[r]);  // masked -> exp(-inf)=0
        rs[r] += p;
        Ps[wave][(quad * 4 + r) * 32 + ng * 16 + l15] = f2b(p);
      }
    }
#pragma unroll
    for (int r = 0; r < 4; ++r) {
#pragma unroll
      for (int off = 1; off < 16; off <<= 1)
        rs[r] += __shfl_xor(rs[r], off);
      l_r[r] += rs[r];
    }
    __syncthreads();  // P visible (also keeps waves converged before restage)

    // O += P V  (A=P[16,32], B=V[32,16] per d-group from V^T tile)
    bf16x8 pf = *(const bf16x8*)&Ps[wave][l15 * 32 + quad * 8];
#pragma unroll
    for (int dg = 0; dg < 4; ++dg) {
      bf16x8 vf = *(const bf16x8*)&Vs[(dg * 16 + l15) * 32 + quad * 8];
      o[dg] = mfma16(pf, vf, o[dg]);
    }
  }

  // epilogue: y[b*T+t][h*64+d] = o/l  (bf16)
  const int b = bh >> 4, h = bh & 15;
#pragma unroll
  for (int dg = 0; dg < 4; ++dg) {
#pragma unroll
    for (int r = 0; r < 4; ++r) {
      int t = qs + quad * 4 + r;
      int col = h * HD + dg * 16 + l15;
      y[(size_t)(b * TT + t) * CC + col] = f2b(o[dg][r] / l_r[r]);
    }
  }
}

extern "C" void kernel_launch(void* const* d_in, const int* in_sizes, int n_in,
                              void* d_out, int out_size, void* d_ws, size_t ws_size,
                              hipStream_t stream) {
  const float* x  = (const float*)d_in[0];
  const float* Wa = (const float*)d_in[1];
  const float* ba = (const float*)d_in[2];
  const float* Wp = (const float*)d_in[3];
  const float* bp = (const float*)d_in[4];
  float* out = (float*)d_out;

  char* ws = (char*)d_ws;
  // workspace layout (bytes)
  ushort_t* xb  = (ushort_t*)(ws + 0);          // 4096*1024 bf16 = 8 MB
  ushort_t* wat = (ushort_t*)(ws + 8388608);    // 3072*1024 bf16 = 6 MB
  ushort_t* wpt = (ushort_t*)(ws + 14680064);   // 1024*1024 bf16 = 2 MB
  ushort_t* qbf = (ushort_t*)(ws + 16777216);   // [B,H,T,64]   8 MB
  ushort_t* kbf = (ushort_t*)(ws + 25165824);   // [B,H,T,64]   8 MB
  ushort_t* vtb = (ushort_t*)(ws + 33554432);   // [B,H,64,T]   8 MB
  ushort_t* yb  = (ushort_t*)(ws + 41943040);   // [4096,1024]  8 MB

  // 1) casts / transposes
  cast_f32_bf16<<<(MM * CC / 4 + 255) / 256, 256, 0, stream>>>(x, xb, MM * CC / 4);
  transpose_cast<<<dim3(N3C / 32, CC / 32), dim3(32, 8), 0, stream>>>(Wa, wat, CC, N3C);
  transpose_cast<<<dim3(CC / 32, CC / 32), dim3(32, 8), 0, stream>>>(Wp, wpt, CC, CC);

  // 2) QKV GEMM with scatter epilogue (RoPE is per-head-constant rotation of q,k
  //    => exactly cancels in q.k^T; v untouched => identity on output, skipped)
  gemm_bt<0><<<dim3(N3C / 128, MM / 128), 256, 0, stream>>>(
      xb, wat, ba, qbf, kbf, vtb, nullptr, N3C, CC);

  // 3) causal flash attention
  attn_kernel<<<dim3(TT / 64, BB * HH), 256, 0, stream>>>(qbf, kbf, vtb, yb);

  // 4) output projection
  gemm_bt<1><<<dim3(CC / 128, MM / 128), 256, 0, stream>>>(
      yb, wpt, bp, nullptr, nullptr, nullptr, out, CC, CC);
}

// Round 2
// 207.048 us; speedup vs baseline: 1.6380x; 1.6380x over previous
//
#include <hip/hip_runtime.h>

typedef __attribute__((ext_vector_type(8))) short bf16x8;
typedef __attribute__((ext_vector_type(4))) float f32x4;
typedef __attribute__((ext_vector_type(4))) unsigned int uint4v;
typedef unsigned short ushort_t;

// Problem constants
#define BB 2
#define TT 2048
#define CC 1024
#define HH 16
#define HD 64
#define MM (BB * TT)       // 4096
#define N3C (3 * CC)       // 3072

__device__ __forceinline__ ushort_t f2b(float f) {
  unsigned u = __builtin_bit_cast(unsigned, f);
  u += 0x7fffu + ((u >> 16) & 1u);   // RNE
  return (ushort_t)(u >> 16);
}

__device__ __forceinline__ f32x4 mfma16(bf16x8 a, bf16x8 b, f32x4 c) {
  return __builtin_amdgcn_mfma_f32_16x16x32_bf16(a, b, c, 0, 0, 0);
}

__device__ __forceinline__ void load_lds16(const void* g, void* l) {
  __builtin_amdgcn_global_load_lds((const __attribute__((address_space(1))) void*)g,
                                   (__attribute__((address_space(3))) void*)l, 16, 0, 0);
}

// ---------------- cast x (f32 -> bf16), 4 elems/thread ----------------
__global__ __launch_bounds__(256) void cast_f32_bf16(const float* __restrict__ x,
                                                     ushort_t* __restrict__ o, int n4) {
  int i = blockIdx.x * 256 + threadIdx.x;
  if (i >= n4) return;
  const float4 v = ((const float4*)x)[i];
  typedef __attribute__((ext_vector_type(4))) ushort_t us4;
  us4 r;
  r.x = f2b(v.x); r.y = f2b(v.y); r.z = f2b(v.z); r.w = f2b(v.w);
  ((us4*)o)[i] = r;
}

// ------------- transpose + cast: W[R,Nc] f32 -> Wt[Nc,R] bf16 -------------
__global__ __launch_bounds__(256) void transpose_cast(const float* __restrict__ W,
                                                      ushort_t* __restrict__ Wt,
                                                      int R, int Nc) {
  __shared__ ushort_t tile[32][33];
  int n0 = blockIdx.x * 32, r0 = blockIdx.y * 32;
  int c = threadIdx.x, rr = threadIdx.y;  // 32 x 8
#pragma unroll
  for (int i = 0; i < 4; ++i) {
    int r = rr + i * 8;
    tile[r][c] = f2b(W[(size_t)(r0 + r) * Nc + n0 + c]);
  }
  __syncthreads();
#pragma unroll
  for (int i = 0; i < 4; ++i) {
    int r = rr + i * 8;  // n-index within block
    Wt[(size_t)(n0 + r) * R + r0 + c] = tile[c][r];
  }
}

// ---------------- MFMA GEMM: C[M,N] = A[M,K] * Bt[N,K]^T + bias ----------------
// EPI 0: scatter bf16 into fragment-native layouts Qf / Kf / Vf (see attn_kernel)
// EPI 1: write f32 out[M,N]
template <int EPI>
__global__ __launch_bounds__(256) void gemm_bt(const ushort_t* __restrict__ A,
                                               const ushort_t* __restrict__ Bt,
                                               const float* __restrict__ bias,
                                               ushort_t* __restrict__ qo,
                                               ushort_t* __restrict__ ko,
                                               ushort_t* __restrict__ vto,
                                               float* __restrict__ outp,
                                               int N, int K) {
  __shared__ __align__(16) ushort_t As[128 * 32];
  __shared__ __align__(16) ushort_t Bs[128 * 32];
  const int tid = threadIdx.x, lane = tid & 63, wave = tid >> 6;
  const int l15 = lane & 15, quad = lane >> 4;
  const int wm = (wave >> 1) * 64, wn = (wave & 1) * 64;
  const int m0 = blockIdx.y * 128, n0 = blockIdx.x * 128;

  f32x4 acc[4][4] = {};
  for (int k0 = 0; k0 < K; k0 += 32) {
    __syncthreads();
#pragma unroll
    for (int p = 0; p < 2; ++p) {
      int e = (p * 256 + tid) * 8;
      int r = e >> 5, c = e & 31;
      load_lds16(&A[(size_t)(m0 + r) * K + k0 + c], &As[e]);
      load_lds16(&Bt[(size_t)(n0 + r) * K + k0 + c], &Bs[e]);
    }
    __syncthreads();
    bf16x8 af[4], bfr[4];
#pragma unroll
    for (int i = 0; i < 4; ++i) {
      af[i]  = *(const bf16x8*)&As[(wm + i * 16 + l15) * 32 + quad * 8];
      bfr[i] = *(const bf16x8*)&Bs[(wn + i * 16 + l15) * 32 + quad * 8];
    }
#pragma unroll
    for (int i = 0; i < 4; ++i)
#pragma unroll
      for (int j = 0; j < 4; ++j)
        acc[i][j] = mfma16(af[i], bfr[j], acc[i][j]);
  }

#pragma unroll
  for (int i = 0; i < 4; ++i) {
#pragma unroll
    for (int j = 0; j < 4; ++j) {
#pragma unroll
      for (int r = 0; r < 4; ++r) {
        int gr = m0 + wm + i * 16 + quad * 4 + r;   // row: C/D row = quad*4+reg
        int gc = n0 + wn + j * 16 + l15;            // col: C/D col = lane&15
        float v = acc[i][j][r] + bias[gc];
        if (EPI == 0) {
          int sec = gc >> 10, cc = gc & 1023, h = cc >> 6, d = cc & 63;
          int b = gr >> 11, t = gr & 2047;
          int bh = b * HH + h;
          ushort_t hv = f2b(v);
          if (sec == 0) {
            // Qf: ((bh*128 + t/16)*2 + d/32)*512 + ((d>>3)&3)*128 + (t&15)*8 + (d&7)
            int si = t >> 4, lq = t & 15, dh = d >> 5, qd = (d >> 3) & 3, j8 = d & 7;
            qo[((((size_t)bh * 128 + si) * 2 + dh) * 64 + qd * 16 + lq) * 8 + j8] = hv;
          } else if (sec == 1) {
            // Kf: ((bh*32 + t/64)*8 + ((t>>4)&3)*2 + d/32)*512 + ...
            int kbi = t >> 6, ng = (t >> 4) & 3, lk = t & 15;
            int dh = d >> 5, qd = (d >> 3) & 3, j8 = d & 7;
            ko[((((size_t)bh * 32 + kbi) * 8 + ng * 2 + dh) * 64 + qd * 16 + lk) * 8 + j8] = hv;
          } else {
            // Vf: key t -> (kbi, h_=bit5, jh=bit4, quad=bits3:2, j03=bits1:0)
            int kbi = t >> 6, kk = t & 63;
            int h_ = kk >> 5, jh = (kk >> 4) & 1, qd = (kk >> 2) & 3, j8 = jh * 4 + (kk & 3);
            int dg = d >> 4, lv = d & 15;
            vto[((((size_t)bh * 32 + kbi) * 8 + dg * 2 + h_) * 64 + qd * 16 + lv) * 8 + j8] = hv;
          }
        } else {
          outp[(size_t)gr * N + gc] = v;
        }
      }
    }
  }
}

// ---------------- flash attention (causal), wave-independent, no LDS ----------------
// One wave = one 32-query block of one (b,h). S^T = mfma(K,Q); P stays in-lane for PV
// via contraction-permutation; O^T = mfma(V^T, P). Longest blocks dispatched first.
__global__ __launch_bounds__(256) void attn_kernel(const ushort_t* __restrict__ Qf,
                                                   const ushort_t* __restrict__ Kf,
                                                   const ushort_t* __restrict__ Vf,
                                                   ushort_t* __restrict__ y) {
  const int tid = threadIdx.x, lane = tid & 63, wave = tid >> 6;
  const int l15 = lane & 15, quad = lane >> 4;
  const int gw = blockIdx.x * 4 + wave;          // 0..2047
  const int bh = gw & 31;
  const int s32 = 63 - (gw >> 5);                // longest first
  const int qs = s32 * 32;
  const int nk = (qs + 95) >> 6;                 // 64-key tiles

  // Q B-frags [strip][dhalf]
  const ushort_t* qbase = Qf + (((size_t)bh * 128 + (qs >> 4)) * 2 * 64 + lane) * 8;
  bf16x8 qf[2][2];
#pragma unroll
  for (int st = 0; st < 2; ++st)
#pragma unroll
    for (int dh = 0; dh < 2; ++dh)
      qf[st][dh] = *(const bf16x8*)(qbase + (st * 2 + dh) * 512);

  f32x4 o[2][4] = {};
  float m_r[2] = {-__builtin_inff(), -__builtin_inff()};
  float l_r[2] = {0.f, 0.f};

  for (int it = 0; it < nk; ++it) {
    const bool last = (it == nk - 1);
    const size_t tb = ((size_t)bh * 32 + it) * 8 * 512 + (size_t)lane * 8;
    // K frags [ng][dh], V^T frags [dg][h] — all coalesced dwordx4
    bf16x8 kf[4][2], vf[4][2];
#pragma unroll
    for (int ng = 0; ng < 4; ++ng)
#pragma unroll
      for (int dh = 0; dh < 2; ++dh)
        kf[ng][dh] = *(const bf16x8*)(Kf + tb + (ng * 2 + dh) * 512);
#pragma unroll
    for (int dg = 0; dg < 4; ++dg)
#pragma unroll
      for (int h = 0; h < 2; ++h)
        vf[dg][h] = *(const bf16x8*)(Vf + tb + (dg * 2 + h) * 512);

#pragma unroll
    for (int st = 0; st < 2; ++st) {
      // S^T: rows = keys (quad*4+r), cols = queries (l15)
      f32x4 s[4];
#pragma unroll
      for (int ng = 0; ng < 4; ++ng) {
        f32x4 z = {};
        z = mfma16(kf[ng][0], qf[st][0], z);
        z = mfma16(kf[ng][1], qf[st][1], z);
        s[ng] = z;
      }
      const int qg = qs + st * 16 + l15;
      float tmax = -__builtin_inff();
#pragma unroll
      for (int ng = 0; ng < 4; ++ng)
#pragma unroll
        for (int r = 0; r < 4; ++r) {
          float v = s[ng][r] * 0.125f;
          if (last) {
            int kg = it * 64 + ng * 16 + quad * 4 + r;
            v = (kg > qg) ? -__builtin_inff() : v;
          }
          s[ng][r] = v;
          tmax = fmaxf(tmax, v);
        }
      tmax = fmaxf(tmax, __shfl_xor(tmax, 16));
      tmax = fmaxf(tmax, __shfl_xor(tmax, 32));
      const float mn = fmaxf(m_r[st], tmax);
      const float a = __expf(m_r[st] - mn);
      m_r[st] = mn;

      float p[4][4];
      float rs = 0.f;
#pragma unroll
      for (int ng = 0; ng < 4; ++ng)
#pragma unroll
        for (int r = 0; r < 4; ++r) {
          float pv = __expf(s[ng][r] - mn);
          p[ng][r] = pv;
          rs += pv;
        }
      rs += __shfl_xor(rs, 16);
      rs += __shfl_xor(rs, 32);
      l_r[st] = l_r[st] * a + rs;

      // pack P into PV B-frags: frag h element j = p[2h + (j>>2)][j&3]
      union { bf16x8 v; ushort_t u[8]; } pk0, pk1;
#pragma unroll
      for (int j = 0; j < 4; ++j) {
        pk0.u[j]     = f2b(p[0][j]);
        pk0.u[j + 4] = f2b(p[1][j]);
        pk1.u[j]     = f2b(p[2][j]);
        pk1.u[j + 4] = f2b(p[3][j]);
      }
#pragma unroll
      for (int dg = 0; dg < 4; ++dg) {
        o[st][dg] *= a;
        o[st][dg] = mfma16(vf[dg][0], pk0.v, o[st][dg]);
        o[st][dg] = mfma16(vf[dg][1], pk1.v, o[st][dg]);
      }
    }
  }

  // epilogue: O^T regs: d = dg*16 + quad*4 + r, query = qs + st*16 + l15
  const int b = bh >> 4, h = bh & 15;
#pragma unroll
  for (int st = 0; st < 2; ++st) {
    const float inv = 1.0f / l_r[st];
    const size_t row = (size_t)(b * TT + qs + st * 16 + l15) * CC;
#pragma unroll
    for (int dg = 0; dg < 4; ++dg) {
      uint2 u;
      u.x = (unsigned)f2b(o[st][dg][0] * inv) | ((unsigned)f2b(o[st][dg][1] * inv) << 16);
      u.y = (unsigned)f2b(o[st][dg][2] * inv) | ((unsigned)f2b(o[st][dg][3] * inv) << 16);
      *(uint2*)&y[row + h * HD + dg * 16 + quad * 4] = u;
    }
  }
}

extern "C" void kernel_launch(void* const* d_in, const int* in_sizes, int n_in,
                              void* d_out, int out_size, void* d_ws, size_t ws_size,
                              hipStream_t stream) {
  const float* x  = (const float*)d_in[0];
  const float* Wa = (const float*)d_in[1];
  const float* ba = (const float*)d_in[2];
  const float* Wp = (const float*)d_in[3];
  const float* bp = (const float*)d_in[4];
  float* out = (float*)d_out;

  char* ws = (char*)d_ws;
  ushort_t* xb  = (ushort_t*)(ws + 0);          // 8 MB
  ushort_t* wat = (ushort_t*)(ws + 8388608);    // 6 MB
  ushort_t* wpt = (ushort_t*)(ws + 14680064);   // 2 MB
  ushort_t* Qf  = (ushort_t*)(ws + 16777216);   // 8 MB fragment-native
  ushort_t* Kf  = (ushort_t*)(ws + 25165824);   // 8 MB
  ushort_t* Vf  = (ushort_t*)(ws + 33554432);   // 8 MB
  ushort_t* yb  = (ushort_t*)(ws + 41943040);   // 8 MB

  cast_f32_bf16<<<(MM * CC / 4 + 255) / 256, 256, 0, stream>>>(x, xb, MM * CC / 4);
  transpose_cast<<<dim3(N3C / 32, CC / 32), dim3(32, 8), 0, stream>>>(Wa, wat, CC, N3C);
  transpose_cast<<<dim3(CC / 32, CC / 32), dim3(32, 8), 0, stream>>>(Wp, wpt, CC, CC);

  // QKV GEMM with fragment-native scatter epilogue (RoPE cancels exactly; skipped)
  gemm_bt<0><<<dim3(N3C / 128, MM / 128), 256, 0, stream>>>(
      xb, wat, ba, Qf, Kf, Vf, nullptr, N3C, CC);

  attn_kernel<<<512, 256, 0, stream>>>(Qf, Kf, Vf, yb);

  gemm_bt<1><<<dim3(CC / 128, MM / 128), 256, 0, stream>>>(
      yb, wpt, bp, nullptr, nullptr, nullptr, out, CC, CC);
}